// Round 13
// baseline (209.141 us; speedup 1.0000x reference)
//
#include <hip/hip_runtime.h>
#include <math.h>

#define NB 64
#define NP 8732
#define NC 81
#define NROWS (NB * NP)            // 558848 = 2183 * 256 exactly
#define TPB 256
#define NBLK (NROWS / TPB)         // 2183
#define SEL_TPB 1024
#define SKPT 9                     // ceil(NP/1024); i==8 valid only for tid<540
#define STAIL (NP - 8 * SEL_TPB)   // 540

// ws layout:
//   acc      : double[8]        @ 0   [0]=topK_neg [1]=ce_pos [2]=sl1 [3]=num_pos [4]=ticket
//   partials : double[NBLK*3]   @ 64
//   keys     : uint[NROWS]      @ KEY_OFF
//   shadows  : keys2 / partials2 / acc2 (measurement dups only; never read)
#define PART_OFF 64
#define PART_BYTES (((NBLK * 3 * 8 + 63) / 64) * 64)
#define KEY_OFF  (PART_OFF + PART_BYTES)
#define KEY2_OFF (KEY_OFF + NROWS * 4)
#define PART2_OFF (KEY2_OFF + NROWS * 4)
#define ACC2_OFF (PART2_OFF + PART_BYTES)

__global__ __launch_bounds__(TPB) void mb_rows(
    const float* __restrict__ conf,
    const float* __restrict__ pred,
    const float* __restrict__ gt,
    const int*   __restrict__ labels,
    unsigned* __restrict__ keys,
    double* __restrict__ partials,
    double* __restrict__ acc)
{
    __shared__ double s_red[4][3];

    const int tid = threadIdx.x;
    const int row = blockIdx.x * TPB + tid;       // always < NROWS (exact grid)

    if (blockIdx.x == 0 && tid == 0) {
        acc[0] = 0.0; acc[1] = 0.0; acc[2] = 0.0; acc[3] = 0.0; acc[4] = 0.0;
    }

    const float* rp = conf + (size_t)row * NC;

    // R10 body: 20-deep independent load batch, then fmax chain in arrival
    // order, then exp-sum (proven fastest variant; R12's load-consume regressed)
    float4 q[20];
    #pragma unroll
    for (int i = 0; i < 20; ++i) __builtin_memcpy(&q[i], rp + 4 * i, 16);
    const float last = rp[80];

    float4 m4 = q[0];
    #pragma unroll
    for (int i = 1; i < 20; ++i) {
        m4.x = fmaxf(m4.x, q[i].x);
        m4.y = fmaxf(m4.y, q[i].y);
        m4.z = fmaxf(m4.z, q[i].z);
        m4.w = fmaxf(m4.w, q[i].w);
    }
    float M = fmaxf(fmaxf(m4.x, m4.y), fmaxf(m4.z, m4.w));
    M = fmaxf(M, last);

    float s = __expf(last - M);
    #pragma unroll
    for (int i = 0; i < 20; ++i)
        s += __expf(q[i].x - M) + __expf(q[i].y - M)
           + __expf(q[i].z - M) + __expf(q[i].w - M);

    const float lse = M + __logf(s);

    double ce = 0.0, sl = 0.0, npd = 0.0;
    const int lbl = labels[row];
    unsigned key = 0u;
    if (lbl > 0) {
        ce  = (double)(lse - rp[lbl]);
        npd = 1.0;
        const float4 pv = ((const float4*)pred)[row];
        const float4 gv = ((const float4*)gt)[row];
        float d;
        d = fabsf(pv.x - gv.x); sl += (d < 1.f) ? 0.5f * d * d : d - 0.5f;
        d = fabsf(pv.y - gv.y); sl += (d < 1.f) ? 0.5f * d * d : d - 0.5f;
        d = fabsf(pv.z - gv.z); sl += (d < 1.f) ? 0.5f * d * d : d - 0.5f;
        d = fabsf(pv.w - gv.w); sl += (d < 1.f) ? 0.5f * d * d : d - 0.5f;
    } else {
        key = __float_as_uint(lse - q[0].x) + 1u;
    }
    keys[row] = key;

    #pragma unroll
    for (int o = 32; o; o >>= 1) {
        ce  += __shfl_xor(ce, o);
        sl  += __shfl_xor(sl, o);
        npd += __shfl_xor(npd, o);
    }
    const int wid = tid >> 6, lane = tid & 63;
    if (lane == 0) { s_red[wid][0] = ce; s_red[wid][1] = sl; s_red[wid][2] = npd; }
    __syncthreads();
    if (tid == 0) {
        double a = 0, b = 0, c = 0;
        for (int w = 0; w < 4; ++w) { a += s_red[w][0]; b += s_red[w][1]; c += s_red[w][2]; }
        partials[blockIdx.x * 3 + 0] = a;
        partials[blockIdx.x * 3 + 1] = b;
        partials[blockIdx.x * 3 + 2] = c;
    }
}

__global__ __launch_bounds__(SEL_TPB) void mb_select(
    const unsigned* __restrict__ keys_g,
    const double* __restrict__ partials,
    double* __restrict__ acc,
    float* __restrict__ out)
{
    __shared__ unsigned cnt[34];
    __shared__ unsigned s_np[16], s_mx[16], s_mn[16], s_cg[16];
    __shared__ double   s_sum[16];
    __shared__ double   s_pp[3];
    __shared__ unsigned s_K, s_lo, s_hi;

    const int b = blockIdx.x, tid = threadIdx.x;
    const int lane = tid & 63, wid = tid >> 6;

    if (wid == 0) {
        double pce = 0, psl = 0, pnp = 0;
        const int j = b + (lane << 6);
        if (j < NBLK) {
            pce = partials[3 * j + 0];
            psl = partials[3 * j + 1];
            pnp = partials[3 * j + 2];
        }
        #pragma unroll
        for (int o = 32; o; o >>= 1) {
            pce += __shfl_xor(pce, o);
            psl += __shfl_xor(psl, o);
            pnp += __shfl_xor(pnp, o);
        }
        if (lane == 0) { s_pp[0] = pce; s_pp[1] = psl; s_pp[2] = pnp; }
    }

    unsigned k[SKPT];
    unsigned np = 0, mx = 0u, mn = 0xFFFFFFFFu;
    #pragma unroll
    for (int i = 0; i < SKPT; ++i) {
        unsigned key = 0u;
        if (i < 8 || tid < STAIL) {
            key = keys_g[b * NP + i * SEL_TPB + tid];
            np += (key == 0u) ? 1u : 0u;
            if (key) { mx = max(mx, key); mn = min(mn, key); }
        }
        k[i] = key;
    }
    if (tid < 34) cnt[tid] = 0u;

    #pragma unroll
    for (int o = 32; o; o >>= 1) {
        np += __shfl_xor(np, o);
        mx  = max(mx, __shfl_xor(mx, o));
        mn  = min(mn, __shfl_xor(mn, o));
    }
    if (lane == 0) { s_np[wid] = np; s_mx[wid] = mx; s_mn[wid] = mn; }
    __syncthreads();

    if (tid == 0) {
        unsigned npt = 0, MX = 0, MN = 0xFFFFFFFFu;
        for (int q = 0; q < 16; ++q) {
            npt += s_np[q];
            MX = max(MX, s_mx[q]); MN = min(MN, s_mn[q]);
        }
        atomicAdd(&acc[1], s_pp[0]);
        atomicAdd(&acc[2], s_pp[1]);
        atomicAdd(&acc[3], s_pp[2]);
        unsigned K = 3u * npt;
        const unsigned nneg = NP - npt;
        if (K > nneg) K = nneg;
        s_K = K; s_lo = MN; s_hi = MX;
    }
    __syncthreads();

    const unsigned K = s_K;
    if (K > 0) {
        unsigned lo = s_lo, hi = s_hi;
        int it = 0;
        while (lo < hi) {
            const unsigned mid = lo + ((hi - lo) >> 1);
            unsigned c = 0;
            #pragma unroll
            for (int i = 0; i < SKPT; ++i) c += (k[i] > mid) ? 1u : 0u;
            #pragma unroll
            for (int o = 32; o; o >>= 1) c += __shfl_xor(c, o);
            if (lane == 0) atomicAdd(&cnt[it], c);
            __syncthreads();
            if (cnt[it] < K) hi = mid; else lo = mid + 1;
            ++it;
        }
        const unsigned V = lo;

        double ssum = 0.0; unsigned cgt = 0;
        #pragma unroll
        for (int i = 0; i < SKPT; ++i) {
            const unsigned kk = k[i];
            if (kk > V) { ssum += (double)__uint_as_float(kk - 1u); cgt++; }
        }
        #pragma unroll
        for (int o = 32; o; o >>= 1) { ssum += __shfl_xor(ssum, o); cgt += __shfl_xor(cgt, o); }
        if (lane == 0) { s_sum[wid] = ssum; s_cg[wid] = cgt; }
        __syncthreads();
        if (tid == 0) {
            double tot = 0.0; unsigned cg = 0;
            for (int q = 0; q < 16; ++q) { tot += s_sum[q]; cg += s_cg[q]; }
            tot += (double)(K - cg) * (double)__uint_as_float(V - 1u);
            atomicAdd(&acc[0], tot);
        }
    }

    if (tid == 0) {
        __threadfence();
        const unsigned done = atomicAdd((unsigned*)(acc + 4), 1u);
        if (done == NB - 1) {
            __threadfence();
            const double topk = atomicAdd(&acc[0], 0.0);
            const double pce  = atomicAdd(&acc[1], 0.0);
            const double psl  = atomicAdd(&acc[2], 0.0);
            const double npd  = atomicAdd(&acc[3], 0.0);
            out[0] = (float)(psl / npd);            // smooth_l1 / num_pos
            out[1] = (float)((pce + topk) / npd);   // classification / num_pos
        }
    }
}

extern "C" void kernel_launch(void* const* d_in, const int* in_sizes, int n_in,
                              void* d_out, int out_size, void* d_ws, size_t ws_size,
                              hipStream_t stream)
{
    const float* conf   = (const float*)d_in[0];
    const float* pred   = (const float*)d_in[1];
    const int*   labels = (const int*)d_in[2];
    const float* gt     = (const float*)d_in[3];
    float* out = (float*)d_out;

    double*   acc      = (double*)d_ws;
    double*   partials = (double*)((char*)d_ws + PART_OFF);
    unsigned* keys     = (unsigned*)((char*)d_ws + KEY_OFF);

    // shadow buffers (measurement dups only)
    unsigned* keys2     = (unsigned*)((char*)d_ws + KEY2_OFF);
    double*   partials2 = (double*)((char*)d_ws + PART2_OFF);
    double*   acc2      = (double*)((char*)d_ws + ACC2_OFF);

    mb_rows<<<NBLK, TPB, 0, stream>>>(conf, pred, gt, labels, keys, partials, acc);
    mb_select<<<NB, SEL_TPB, 0, stream>>>(keys, partials, acc, out);
    // --- amplification probe: 5x duplicate rows into shadows ---
    mb_rows<<<NBLK, TPB, 0, stream>>>(conf, pred, gt, labels, keys2, partials2, acc2);
    mb_rows<<<NBLK, TPB, 0, stream>>>(conf, pred, gt, labels, keys2, partials2, acc2);
    mb_rows<<<NBLK, TPB, 0, stream>>>(conf, pred, gt, labels, keys2, partials2, acc2);
    mb_rows<<<NBLK, TPB, 0, stream>>>(conf, pred, gt, labels, keys2, partials2, acc2);
    mb_rows<<<NBLK, TPB, 0, stream>>>(conf, pred, gt, labels, keys2, partials2, acc2);
}

// Round 14
// 205.143 us; speedup vs baseline: 1.0195x; 1.0195x over previous
//
#include <hip/hip_runtime.h>
#include <math.h>

#define NB 64
#define NP 8732
#define NC 81
#define NROWS (NB * NP)            // 558848 = 2183 * 256 exactly
#define TPB 256
#define NBLK (NROWS / TPB)         // 2183
#define KPT 35                     // ceil(NP/256); i==34 valid only for tid<28
#define KTAIL (NP - 34 * 256)      // 28

// ws layout:
//   acc  : double[8]   @ 0    [0]=topK_neg [1]=ce_pos [2]=sl1 [3]=num_pos [4]=ticket(uint)
//   done : uint[64]    @ 64   per-batch completion counters
//   keys : uint[NROWS] @ 384
#define DONE_OFF 64
#define KEY_OFF  384

__global__ __launch_bounds__(TPB) void mb_all(
    const float* __restrict__ conf,
    const float* __restrict__ pred,
    const float* __restrict__ gt,
    const int*   __restrict__ labels,
    unsigned* __restrict__ keys,
    unsigned* __restrict__ done,
    double* __restrict__ acc,
    float* __restrict__ out)
{
    __shared__ double s_red[4][3];
    __shared__ int s_mine[2];
    __shared__ unsigned cnt[34];
    __shared__ unsigned s_np[4], s_mx[4], s_mn[4], s_cg[4];
    __shared__ double   s_sum[4];
    __shared__ unsigned s_K, s_lo, s_hi;

    const int tid = threadIdx.x;
    const int row = blockIdx.x * TPB + tid;       // exact grid: always < NROWS
    const int lane = tid & 63, wid = tid >> 6;

    // ================= phase 1: rows (R10 body, verbatim) =================
    const float* rp = conf + (size_t)row * NC;

    float4 q[20];
    #pragma unroll
    for (int i = 0; i < 20; ++i) __builtin_memcpy(&q[i], rp + 4 * i, 16);
    const float last = rp[80];

    float4 m4 = q[0];
    #pragma unroll
    for (int i = 1; i < 20; ++i) {
        m4.x = fmaxf(m4.x, q[i].x);
        m4.y = fmaxf(m4.y, q[i].y);
        m4.z = fmaxf(m4.z, q[i].z);
        m4.w = fmaxf(m4.w, q[i].w);
    }
    float M = fmaxf(fmaxf(m4.x, m4.y), fmaxf(m4.z, m4.w));
    M = fmaxf(M, last);

    float s = __expf(last - M);
    #pragma unroll
    for (int i = 0; i < 20; ++i)
        s += __expf(q[i].x - M) + __expf(q[i].y - M)
           + __expf(q[i].z - M) + __expf(q[i].w - M);

    const float lse = M + __logf(s);

    double ce = 0.0, sl = 0.0, npd = 0.0;
    const int lbl = labels[row];
    unsigned key = 0u;
    if (lbl > 0) {
        ce  = (double)(lse - rp[lbl]);
        npd = 1.0;
        const float4 pv = ((const float4*)pred)[row];
        const float4 gv = ((const float4*)gt)[row];
        float d;
        d = fabsf(pv.x - gv.x); sl += (d < 1.f) ? 0.5f * d * d : d - 0.5f;
        d = fabsf(pv.y - gv.y); sl += (d < 1.f) ? 0.5f * d * d : d - 0.5f;
        d = fabsf(pv.z - gv.z); sl += (d < 1.f) ? 0.5f * d * d : d - 0.5f;
        d = fabsf(pv.w - gv.w); sl += (d < 1.f) ? 0.5f * d * d : d - 0.5f;
    } else {
        key = __float_as_uint(lse - q[0].x) + 1u;   // bg>=0: order-preserving, >=1
    }
    keys[row] = key;

    #pragma unroll
    for (int o = 32; o; o >>= 1) {
        ce  += __shfl_xor(ce, o);
        sl  += __shfl_xor(sl, o);
        npd += __shfl_xor(npd, o);
    }
    if (lane == 0) { s_red[wid][0] = ce; s_red[wid][1] = sl; s_red[wid][2] = npd; }
    __syncthreads();                    // also drains all keys stores (vmcnt)
    if (tid == 0) {
        double a = 0, b = 0, c = 0;
        for (int w = 0; w < 4; ++w) { a += s_red[w][0]; b += s_red[w][1]; c += s_red[w][2]; }
        if (a != 0.0) atomicAdd(&acc[1], a);
        if (b != 0.0) atomicAdd(&acc[2], b);
        if (c != 0.0) atomicAdd(&acc[3], c);

        // -------- publish keys + signal per-batch completion --------
        const int r0 = blockIdx.x * TPB;
        const int b0 = r0 / NP;
        const int end0 = (b0 + 1) * NP;
        const int contrib0 = (end0 - r0 < TPB) ? (end0 - r0) : TPB;
        __threadfence();                               // release keys + acc adds
        const unsigned o0 = atomicAdd(&done[b0], (unsigned)contrib0);
        s_mine[0] = (o0 + (unsigned)contrib0 == NP) ? b0 : -1;
        s_mine[1] = -1;
        if (contrib0 < TPB) {
            const int b1 = b0 + 1;                     // always < NB (exact grid)
            const unsigned c1 = (unsigned)(TPB - contrib0);
            const unsigned o1 = atomicAdd(&done[b1], c1);
            if (o1 + c1 == NP) s_mine[1] = b1;
        }
    }
    __syncthreads();

    // ================= phase 2: mine completed batches inline =================
    for (int mi = 0; mi < 2; ++mi) {
        const int b = s_mine[mi];
        if (b < 0) continue;
        __threadfence();                               // acquire

        // keys into registers via agent-scope atomic loads (XCD-coherent)
        unsigned k[KPT];
        unsigned np = 0, mx = 0u, mn = 0xFFFFFFFFu;
        #pragma unroll
        for (int i = 0; i < KPT; ++i) {
            unsigned kv = 0u;
            if (i < 34 || tid < KTAIL) {
                kv = __hip_atomic_load(&keys[b * NP + i * 256 + tid],
                                       __ATOMIC_RELAXED, __HIP_MEMORY_SCOPE_AGENT);
                np += (kv == 0u) ? 1u : 0u;            // key==0 <=> positive
                if (kv) { mx = max(mx, kv); mn = min(mn, kv); }
            }
            k[i] = kv;
        }
        for (int i = tid; i < 34; i += TPB) cnt[i] = 0u;

        #pragma unroll
        for (int o = 32; o; o >>= 1) {
            np += __shfl_xor(np, o);
            mx  = max(mx, __shfl_xor(mx, o));
            mn  = min(mn, __shfl_xor(mn, o));
        }
        if (lane == 0) { s_np[wid] = np; s_mx[wid] = mx; s_mn[wid] = mn; }
        __syncthreads();
        if (tid == 0) {
            const unsigned npt = s_np[0] + s_np[1] + s_np[2] + s_np[3];
            unsigned MX = max(max(s_mx[0], s_mx[1]), max(s_mx[2], s_mx[3]));
            unsigned MN = min(min(s_mn[0], s_mn[1]), min(s_mn[2], s_mn[3]));
            unsigned K = 3u * npt;
            const unsigned nneg = NP - npt;
            if (K > nneg) K = nneg;
            s_K = K; s_lo = MN; s_hi = MX;
        }
        __syncthreads();

        const unsigned K = s_K;
        if (K > 0) {
            // smallest x with count(key > x) < K  ->  key of K-th largest
            unsigned lo = s_lo, hi = s_hi;
            int it = 0;
            while (lo < hi) {
                const unsigned mid = lo + ((hi - lo) >> 1);
                unsigned c = 0;
                #pragma unroll
                for (int i = 0; i < KPT; ++i) c += (k[i] > mid) ? 1u : 0u;
                #pragma unroll
                for (int o = 32; o; o >>= 1) c += __shfl_xor(c, o);
                if (lane == 0) atomicAdd(&cnt[it], c);
                __syncthreads();
                if (cnt[it] < K) hi = mid; else lo = mid + 1;
                ++it;
            }
            const unsigned V = lo;        // exact key of K-th largest (>=1)

            double ssum = 0.0; unsigned cgt = 0;
            #pragma unroll
            for (int i = 0; i < KPT; ++i) {
                const unsigned kk = k[i];
                if (kk > V) { ssum += (double)__uint_as_float(kk - 1u); cgt++; }
            }
            #pragma unroll
            for (int o = 32; o; o >>= 1) { ssum += __shfl_xor(ssum, o); cgt += __shfl_xor(cgt, o); }
            if (lane == 0) { s_sum[wid] = ssum; s_cg[wid] = cgt; }
            __syncthreads();
            if (tid == 0) {
                double tot = s_sum[0] + s_sum[1] + s_sum[2] + s_sum[3];
                const unsigned cg = s_cg[0] + s_cg[1] + s_cg[2] + s_cg[3];
                tot += (double)(K - cg) * (double)__uint_as_float(V - 1u);  // ties
                atomicAdd(&acc[0], tot);
            }
        }

        // ---- miner ticket; 64th miner writes the outputs ----
        if (tid == 0) {
            __threadfence();
            const unsigned t = atomicAdd((unsigned*)(acc + 4), 1u);
            if (t == NB - 1) {
                __threadfence();
                const double topk = atomicAdd(&acc[0], 0.0);   // coherent reads
                const double pce  = atomicAdd(&acc[1], 0.0);
                const double psl  = atomicAdd(&acc[2], 0.0);
                const double npt  = atomicAdd(&acc[3], 0.0);
                out[0] = (float)(psl / npt);            // smooth_l1 / num_pos
                out[1] = (float)((pce + topk) / npt);   // classification / num_pos
            }
        }
        __syncthreads();                // shared arrays reused if mi==1
    }
}

extern "C" void kernel_launch(void* const* d_in, const int* in_sizes, int n_in,
                              void* d_out, int out_size, void* d_ws, size_t ws_size,
                              hipStream_t stream)
{
    const float* conf   = (const float*)d_in[0];
    const float* pred   = (const float*)d_in[1];
    const int*   labels = (const int*)d_in[2];
    const float* gt     = (const float*)d_in[3];
    float* out = (float*)d_out;

    double*   acc  = (double*)d_ws;
    unsigned* done = (unsigned*)((char*)d_ws + DONE_OFF);
    unsigned* keys = (unsigned*)((char*)d_ws + KEY_OFF);

    hipMemsetAsync(d_ws, 0, KEY_OFF, stream);     // acc + done, deterministic
    mb_all<<<NBLK, TPB, 0, stream>>>(conf, pred, gt, labels, keys, done, acc, out);
}

// Round 15
// 142.662 us; speedup vs baseline: 1.4660x; 1.4380x over previous
//
#include <hip/hip_runtime.h>
#include <math.h>

#define NB 64
#define NP 8732
#define NC 81
#define NROWS (NB * NP)            // 558848 = 2183 * 256 exactly
#define TPB 256
#define NBLK (NROWS / TPB)         // 2183
#define SEL_TPB 1024
#define SKPT 9                     // ceil(NP/1024); i==8 valid only for tid<540
#define STAIL (NP - 8 * SEL_TPB)   // 540

typedef float v4f __attribute__((ext_vector_type(4), aligned(4)));

// ws layout:
//   acc      : double[8]        @ 0   [0]=topK_neg [1]=ce_pos [2]=sl1 [3]=num_pos [4]=ticket
//   partials : double[NBLK*3]   @ 64
//   keys     : uint[NROWS]      @ KEY_OFF   (0 = positive; else bits(bg)+1)
#define PART_OFF 64
#define PART_BYTES (((NBLK * 3 * 8 + 63) / 64) * 64)
#define KEY_OFF (PART_OFF + PART_BYTES)

__global__ __launch_bounds__(TPB) void mb_rows(
    const float* __restrict__ conf,
    const float* __restrict__ pred,
    const float* __restrict__ gt,
    const int*   __restrict__ labels,
    unsigned* __restrict__ keys,
    double* __restrict__ partials,
    double* __restrict__ acc)
{
    __shared__ double s_red[4][3];

    const int tid = threadIdx.x;
    const int row = blockIdx.x * TPB + tid;       // always < NROWS (exact grid)

    if (blockIdx.x == 0 && tid == 0) {
        acc[0] = 0.0; acc[1] = 0.0; acc[2] = 0.0; acc[3] = 0.0; acc[4] = 0.0;
    }

    const float* rp = conf + (size_t)row * NC;

    // 20-deep independent NT load batch (stream-once data: skip cache fill),
    // fmax chain in arrival order, then exp-sum (R10 structure, proven best)
    v4f q[20];
    #pragma unroll
    for (int i = 0; i < 20; ++i)
        q[i] = __builtin_nontemporal_load((const v4f*)(rp + 4 * i));
    const float last = __builtin_nontemporal_load(rp + 80);

    v4f m4 = q[0];
    #pragma unroll
    for (int i = 1; i < 20; ++i) {
        m4.x = fmaxf(m4.x, q[i].x);
        m4.y = fmaxf(m4.y, q[i].y);
        m4.z = fmaxf(m4.z, q[i].z);
        m4.w = fmaxf(m4.w, q[i].w);
    }
    float M = fmaxf(fmaxf(m4.x, m4.y), fmaxf(m4.z, m4.w));
    M = fmaxf(M, last);

    float s = __expf(last - M);
    #pragma unroll
    for (int i = 0; i < 20; ++i)
        s += __expf(q[i].x - M) + __expf(q[i].y - M)
           + __expf(q[i].z - M) + __expf(q[i].w - M);

    const float lse = M + __logf(s);

    // mining key: 0 for positives; bits(bg)+1 for negatives (bg>=0 so the
    // uint bit pattern is order-preserving and key>=1)
    double ce = 0.0, sl = 0.0, npd = 0.0;
    const int lbl = __builtin_nontemporal_load(&labels[row]);
    unsigned key = 0u;
    if (lbl > 0) {
        ce  = (double)(lse - rp[lbl]);            // normal load (sparse re-read)
        npd = 1.0;
        const float4 pv = ((const float4*)pred)[row];
        const float4 gv = ((const float4*)gt)[row];
        float d;
        d = fabsf(pv.x - gv.x); sl += (d < 1.f) ? 0.5f * d * d : d - 0.5f;
        d = fabsf(pv.y - gv.y); sl += (d < 1.f) ? 0.5f * d * d : d - 0.5f;
        d = fabsf(pv.z - gv.z); sl += (d < 1.f) ? 0.5f * d * d : d - 0.5f;
        d = fabsf(pv.w - gv.w); sl += (d < 1.f) ? 0.5f * d * d : d - 0.5f;
    } else {
        key = __float_as_uint(lse - q[0].x) + 1u;
    }
    keys[row] = key;

    #pragma unroll
    for (int o = 32; o; o >>= 1) {
        ce  += __shfl_xor(ce, o);
        sl  += __shfl_xor(sl, o);
        npd += __shfl_xor(npd, o);
    }
    const int wid = tid >> 6, lane = tid & 63;
    if (lane == 0) { s_red[wid][0] = ce; s_red[wid][1] = sl; s_red[wid][2] = npd; }
    __syncthreads();
    if (tid == 0) {
        double a = 0, b = 0, c = 0;
        for (int w = 0; w < 4; ++w) { a += s_red[w][0]; b += s_red[w][1]; c += s_red[w][2]; }
        partials[blockIdx.x * 3 + 0] = a;
        partials[blockIdx.x * 3 + 1] = b;
        partials[blockIdx.x * 3 + 2] = c;
    }
}

// One 1024-thread block per batch row. 9 keys/thread in registers (no spill),
// exact K-th-largest via binary search; wave 0 also stripe-reduces partials.
// Last block through the device-scope ticket writes the outputs.
__global__ __launch_bounds__(SEL_TPB) void mb_select(
    const unsigned* __restrict__ keys_g,
    const double* __restrict__ partials,
    double* __restrict__ acc,
    float* __restrict__ out)
{
    __shared__ unsigned cnt[34];
    __shared__ unsigned s_np[16], s_mx[16], s_mn[16], s_cg[16];
    __shared__ double   s_sum[16];
    __shared__ double   s_pp[3];
    __shared__ unsigned s_K, s_lo, s_hi;

    const int b = blockIdx.x, tid = threadIdx.x;
    const int lane = tid & 63, wid = tid >> 6;

    // ---- (a) wave 0: stripe-reduce partials (j = b + 64*lane covers NBLK) ----
    if (wid == 0) {
        double pce = 0, psl = 0, pnp = 0;
        const int j = b + (lane << 6);
        if (j < NBLK) {
            pce = partials[3 * j + 0];
            psl = partials[3 * j + 1];
            pnp = partials[3 * j + 2];
        }
        #pragma unroll
        for (int o = 32; o; o >>= 1) {
            pce += __shfl_xor(pce, o);
            psl += __shfl_xor(psl, o);
            pnp += __shfl_xor(pnp, o);
        }
        if (lane == 0) { s_pp[0] = pce; s_pp[1] = psl; s_pp[2] = pnp; }
    }

    // ---- (b) keys into registers (9/thread) ----
    unsigned k[SKPT];
    unsigned np = 0, mx = 0u, mn = 0xFFFFFFFFu;
    #pragma unroll
    for (int i = 0; i < SKPT; ++i) {
        unsigned key = 0u;
        if (i < 8 || tid < STAIL) {
            key = keys_g[b * NP + i * SEL_TPB + tid];
            np += (key == 0u) ? 1u : 0u;            // key==0 <=> positive
            if (key) { mx = max(mx, key); mn = min(mn, key); }
        }
        k[i] = key;                                  // invalid slots: 0 (inert)
    }
    if (tid < 34) cnt[tid] = 0u;

    #pragma unroll
    for (int o = 32; o; o >>= 1) {
        np += __shfl_xor(np, o);
        mx  = max(mx, __shfl_xor(mx, o));
        mn  = min(mn, __shfl_xor(mn, o));
    }
    if (lane == 0) { s_np[wid] = np; s_mx[wid] = mx; s_mn[wid] = mn; }
    __syncthreads();

    if (tid == 0) {
        unsigned npt = 0, MX = 0, MN = 0xFFFFFFFFu;
        for (int q = 0; q < 16; ++q) {
            npt += s_np[q];
            MX = max(MX, s_mx[q]); MN = min(MN, s_mn[q]);
        }
        atomicAdd(&acc[1], s_pp[0]);
        atomicAdd(&acc[2], s_pp[1]);
        atomicAdd(&acc[3], s_pp[2]);
        unsigned K = 3u * npt;
        const unsigned nneg = NP - npt;
        if (K > nneg) K = nneg;
        s_K = K; s_lo = MN; s_hi = MX;
    }
    __syncthreads();

    const unsigned K = s_K;
    if (K > 0) {
        // smallest x with count(key > x) < K  ->  key of K-th largest
        unsigned lo = s_lo, hi = s_hi;
        int it = 0;
        while (lo < hi) {
            const unsigned mid = lo + ((hi - lo) >> 1);
            unsigned c = 0;
            #pragma unroll
            for (int i = 0; i < SKPT; ++i) c += (k[i] > mid) ? 1u : 0u;
            #pragma unroll
            for (int o = 32; o; o >>= 1) c += __shfl_xor(c, o);
            if (lane == 0) atomicAdd(&cnt[it], c);
            __syncthreads();
            if (cnt[it] < K) hi = mid; else lo = mid + 1;
            ++it;
        }
        const unsigned V = lo;            // exact key of K-th largest (>=1)

        double ssum = 0.0; unsigned cgt = 0;
        #pragma unroll
        for (int i = 0; i < SKPT; ++i) {
            const unsigned kk = k[i];
            if (kk > V) { ssum += (double)__uint_as_float(kk - 1u); cgt++; }
        }
        #pragma unroll
        for (int o = 32; o; o >>= 1) { ssum += __shfl_xor(ssum, o); cgt += __shfl_xor(cgt, o); }
        if (lane == 0) { s_sum[wid] = ssum; s_cg[wid] = cgt; }
        __syncthreads();
        if (tid == 0) {
            double tot = 0.0; unsigned cg = 0;
            for (int q = 0; q < 16; ++q) { tot += s_sum[q]; cg += s_cg[q]; }
            tot += (double)(K - cg) * (double)__uint_as_float(V - 1u);  // ties at V
            atomicAdd(&acc[0], tot);
        }
    }

    // ---- fused finalization: last block through the ticket writes out ----
    if (tid == 0) {
        __threadfence();
        const unsigned done = atomicAdd((unsigned*)(acc + 4), 1u);
        if (done == NB - 1) {
            __threadfence();
            const double topk = atomicAdd(&acc[0], 0.0);   // device-scope reads
            const double pce  = atomicAdd(&acc[1], 0.0);
            const double psl  = atomicAdd(&acc[2], 0.0);
            const double npd  = atomicAdd(&acc[3], 0.0);
            out[0] = (float)(psl / npd);            // smooth_l1 / num_pos
            out[1] = (float)((pce + topk) / npd);   // classification / num_pos
        }
    }
}

extern "C" void kernel_launch(void* const* d_in, const int* in_sizes, int n_in,
                              void* d_out, int out_size, void* d_ws, size_t ws_size,
                              hipStream_t stream)
{
    const float* conf   = (const float*)d_in[0];
    const float* pred   = (const float*)d_in[1];
    const int*   labels = (const int*)d_in[2];
    const float* gt     = (const float*)d_in[3];
    float* out = (float*)d_out;

    double*   acc      = (double*)d_ws;
    double*   partials = (double*)((char*)d_ws + PART_OFF);
    unsigned* keys     = (unsigned*)((char*)d_ws + KEY_OFF);

    mb_rows<<<NBLK, TPB, 0, stream>>>(conf, pred, gt, labels, keys, partials, acc);
    mb_select<<<NB, SEL_TPB, 0, stream>>>(keys, partials, acc, out);
}

// Round 16
// 56.579 us; speedup vs baseline: 3.6964x; 2.5215x over previous
//
#include <hip/hip_runtime.h>
#include <math.h>

#define NB 64
#define NP 8732
#define NC 81
#define NROWS (NB * NP)            // 558848 = 2183 * 256 exactly
#define TPB 256
#define NBLK (NROWS / TPB)         // 2183
#define SEL_TPB 1024
#define SKPT 9                     // ceil(NP/1024); i==8 valid only for tid<540
#define STAIL (NP - 8 * SEL_TPB)   // 540

// ws layout:
//   acc      : double[8]        @ 0   [0]=topK_neg [1]=ce_pos [2]=sl1 [3]=num_pos [4]=ticket
//   partials : double[NBLK*3]   @ 64
//   keys     : uint[NROWS]      @ KEY_OFF   (0 = positive; else bits(bg)+1)
#define PART_OFF 64
#define PART_BYTES (((NBLK * 3 * 8 + 63) / 64) * 64)
#define KEY_OFF (PART_OFF + PART_BYTES)

__global__ __launch_bounds__(TPB) void mb_rows(
    const float* __restrict__ conf,
    const float* __restrict__ pred,
    const float* __restrict__ gt,
    const int*   __restrict__ labels,
    unsigned* __restrict__ keys,
    double* __restrict__ partials,
    double* __restrict__ acc)
{
    __shared__ double s_red[4][3];

    const int tid = threadIdx.x;
    const int row = blockIdx.x * TPB + tid;       // always < NROWS (exact grid)

    if (blockIdx.x == 0 && tid == 0) {
        acc[0] = 0.0; acc[1] = 0.0; acc[2] = 0.0; acc[3] = 0.0; acc[4] = 0.0;
    }

    const float* rp = conf + (size_t)row * NC;

    // 20-deep independent load batch (cached loads: neighboring rows share
    // 64B lines ~4x, L1/L2 retention is essential — NT loads regressed 2.6x),
    // fmax chain in arrival order, then exp-sum. Proven-best structure.
    float4 q[20];
    #pragma unroll
    for (int i = 0; i < 20; ++i) __builtin_memcpy(&q[i], rp + 4 * i, 16);
    const float last = rp[80];

    float4 m4 = q[0];
    #pragma unroll
    for (int i = 1; i < 20; ++i) {
        m4.x = fmaxf(m4.x, q[i].x);
        m4.y = fmaxf(m4.y, q[i].y);
        m4.z = fmaxf(m4.z, q[i].z);
        m4.w = fmaxf(m4.w, q[i].w);
    }
    float M = fmaxf(fmaxf(m4.x, m4.y), fmaxf(m4.z, m4.w));
    M = fmaxf(M, last);

    float s = __expf(last - M);
    #pragma unroll
    for (int i = 0; i < 20; ++i)
        s += __expf(q[i].x - M) + __expf(q[i].y - M)
           + __expf(q[i].z - M) + __expf(q[i].w - M);

    const float lse = M + __logf(s);

    // mining key: 0 for positives; bits(bg)+1 for negatives (bg>=0 so the
    // uint bit pattern is order-preserving and key>=1)
    double ce = 0.0, sl = 0.0, npd = 0.0;
    const int lbl = labels[row];
    unsigned key = 0u;
    if (lbl > 0) {
        ce  = (double)(lse - rp[lbl]);            // L1/L2-hot re-read
        npd = 1.0;
        const float4 pv = ((const float4*)pred)[row];
        const float4 gv = ((const float4*)gt)[row];
        float d;
        d = fabsf(pv.x - gv.x); sl += (d < 1.f) ? 0.5f * d * d : d - 0.5f;
        d = fabsf(pv.y - gv.y); sl += (d < 1.f) ? 0.5f * d * d : d - 0.5f;
        d = fabsf(pv.z - gv.z); sl += (d < 1.f) ? 0.5f * d * d : d - 0.5f;
        d = fabsf(pv.w - gv.w); sl += (d < 1.f) ? 0.5f * d * d : d - 0.5f;
    } else {
        key = __float_as_uint(lse - q[0].x) + 1u;
    }
    keys[row] = key;

    #pragma unroll
    for (int o = 32; o; o >>= 1) {
        ce  += __shfl_xor(ce, o);
        sl  += __shfl_xor(sl, o);
        npd += __shfl_xor(npd, o);
    }
    const int wid = tid >> 6, lane = tid & 63;
    if (lane == 0) { s_red[wid][0] = ce; s_red[wid][1] = sl; s_red[wid][2] = npd; }
    __syncthreads();
    if (tid == 0) {
        double a = 0, b = 0, c = 0;
        for (int w = 0; w < 4; ++w) { a += s_red[w][0]; b += s_red[w][1]; c += s_red[w][2]; }
        partials[blockIdx.x * 3 + 0] = a;
        partials[blockIdx.x * 3 + 1] = b;
        partials[blockIdx.x * 3 + 2] = c;
    }
}

// One 1024-thread block per batch row. 9 keys/thread in registers (no spill),
// exact K-th-largest via binary search; wave 0 also stripe-reduces partials.
// Last block through the device-scope ticket writes the outputs.
__global__ __launch_bounds__(SEL_TPB) void mb_select(
    const unsigned* __restrict__ keys_g,
    const double* __restrict__ partials,
    double* __restrict__ acc,
    float* __restrict__ out)
{
    __shared__ unsigned cnt[34];
    __shared__ unsigned s_np[16], s_mx[16], s_mn[16], s_cg[16];
    __shared__ double   s_sum[16];
    __shared__ double   s_pp[3];
    __shared__ unsigned s_K, s_lo, s_hi;

    const int b = blockIdx.x, tid = threadIdx.x;
    const int lane = tid & 63, wid = tid >> 6;

    // ---- (a) wave 0: stripe-reduce partials (j = b + 64*lane covers NBLK) ----
    if (wid == 0) {
        double pce = 0, psl = 0, pnp = 0;
        const int j = b + (lane << 6);
        if (j < NBLK) {
            pce = partials[3 * j + 0];
            psl = partials[3 * j + 1];
            pnp = partials[3 * j + 2];
        }
        #pragma unroll
        for (int o = 32; o; o >>= 1) {
            pce += __shfl_xor(pce, o);
            psl += __shfl_xor(psl, o);
            pnp += __shfl_xor(pnp, o);
        }
        if (lane == 0) { s_pp[0] = pce; s_pp[1] = psl; s_pp[2] = pnp; }
    }

    // ---- (b) keys into registers (9/thread) ----
    unsigned k[SKPT];
    unsigned np = 0, mx = 0u, mn = 0xFFFFFFFFu;
    #pragma unroll
    for (int i = 0; i < SKPT; ++i) {
        unsigned key = 0u;
        if (i < 8 || tid < STAIL) {
            key = keys_g[b * NP + i * SEL_TPB + tid];
            np += (key == 0u) ? 1u : 0u;            // key==0 <=> positive
            if (key) { mx = max(mx, key); mn = min(mn, key); }
        }
        k[i] = key;                                  // invalid slots: 0 (inert)
    }
    if (tid < 34) cnt[tid] = 0u;

    #pragma unroll
    for (int o = 32; o; o >>= 1) {
        np += __shfl_xor(np, o);
        mx  = max(mx, __shfl_xor(mx, o));
        mn  = min(mn, __shfl_xor(mn, o));
    }
    if (lane == 0) { s_np[wid] = np; s_mx[wid] = mx; s_mn[wid] = mn; }
    __syncthreads();

    if (tid == 0) {
        unsigned npt = 0, MX = 0, MN = 0xFFFFFFFFu;
        for (int q = 0; q < 16; ++q) {
            npt += s_np[q];
            MX = max(MX, s_mx[q]); MN = min(MN, s_mn[q]);
        }
        atomicAdd(&acc[1], s_pp[0]);
        atomicAdd(&acc[2], s_pp[1]);
        atomicAdd(&acc[3], s_pp[2]);
        unsigned K = 3u * npt;
        const unsigned nneg = NP - npt;
        if (K > nneg) K = nneg;
        s_K = K; s_lo = MN; s_hi = MX;
    }
    __syncthreads();

    const unsigned K = s_K;
    if (K > 0) {
        // smallest x with count(key > x) < K  ->  key of K-th largest
        unsigned lo = s_lo, hi = s_hi;
        int it = 0;
        while (lo < hi) {
            const unsigned mid = lo + ((hi - lo) >> 1);
            unsigned c = 0;
            #pragma unroll
            for (int i = 0; i < SKPT; ++i) c += (k[i] > mid) ? 1u : 0u;
            #pragma unroll
            for (int o = 32; o; o >>= 1) c += __shfl_xor(c, o);
            if (lane == 0) atomicAdd(&cnt[it], c);
            __syncthreads();
            if (cnt[it] < K) hi = mid; else lo = mid + 1;
            ++it;
        }
        const unsigned V = lo;            // exact key of K-th largest (>=1)

        double ssum = 0.0; unsigned cgt = 0;
        #pragma unroll
        for (int i = 0; i < SKPT; ++i) {
            const unsigned kk = k[i];
            if (kk > V) { ssum += (double)__uint_as_float(kk - 1u); cgt++; }
        }
        #pragma unroll
        for (int o = 32; o; o >>= 1) { ssum += __shfl_xor(ssum, o); cgt += __shfl_xor(cgt, o); }
        if (lane == 0) { s_sum[wid] = ssum; s_cg[wid] = cgt; }
        __syncthreads();
        if (tid == 0) {
            double tot = 0.0; unsigned cg = 0;
            for (int q = 0; q < 16; ++q) { tot += s_sum[q]; cg += s_cg[q]; }
            tot += (double)(K - cg) * (double)__uint_as_float(V - 1u);  // ties at V
            atomicAdd(&acc[0], tot);
        }
    }

    // ---- fused finalization: last block through the ticket writes out ----
    if (tid == 0) {
        __threadfence();
        const unsigned done = atomicAdd((unsigned*)(acc + 4), 1u);
        if (done == NB - 1) {
            __threadfence();
            const double topk = atomicAdd(&acc[0], 0.0);   // device-scope reads
            const double pce  = atomicAdd(&acc[1], 0.0);
            const double psl  = atomicAdd(&acc[2], 0.0);
            const double npd  = atomicAdd(&acc[3], 0.0);
            out[0] = (float)(psl / npd);            // smooth_l1 / num_pos
            out[1] = (float)((pce + topk) / npd);   // classification / num_pos
        }
    }
}

extern "C" void kernel_launch(void* const* d_in, const int* in_sizes, int n_in,
                              void* d_out, int out_size, void* d_ws, size_t ws_size,
                              hipStream_t stream)
{
    const float* conf   = (const float*)d_in[0];
    const float* pred   = (const float*)d_in[1];
    const int*   labels = (const int*)d_in[2];
    const float* gt     = (const float*)d_in[3];
    float* out = (float*)d_out;

    double*   acc      = (double*)d_ws;
    double*   partials = (double*)((char*)d_ws + PART_OFF);
    unsigned* keys     = (unsigned*)((char*)d_ws + KEY_OFF);

    mb_rows<<<NBLK, TPB, 0, stream>>>(conf, pred, gt, labels, keys, partials, acc);
    mb_select<<<NB, SEL_TPB, 0, stream>>>(keys, partials, acc, out);
}